// Round 14
// baseline (12093.786 us; speedup 1.0000x reference)
//
#include <hip/hip_runtime.h>
#include <math.h>

#define B_ 128
#define T_ 128
#define IN_ 75
#define H_ 512
#define C_ 60
#define Q_ 25

// ---------------- workspace layout (bytes) ----------------
constexpr size_t OFF_WHH3 = 0;                        // uint4 [c][256][512] f16 gate-pairs {i,f,g,o}
constexpr size_t SZ_WHH3  = 3ull * 256 * 512 * 16;
constexpr size_t OFF_WX4  = OFF_WHH3 + SZ_WHH3;       // uint4 [256][512] {Wxt,Wht,Wxs,Whs} pairs
constexpr size_t SZ_WX4   = 256ull * 512 * 16;
constexpr size_t OFF_WIH3 = OFF_WX4 + SZ_WX4;         // uint4 [c][38][512] x-part gate-pairs
constexpr size_t SZ_WIH3  = 3ull * 38 * 512 * 16;
constexpr size_t OFF_FT2  = OFF_WIH3 + SZ_WIH3;       // uint2 [38][512] {fct,fc1} pairs
constexpr size_t SZ_FT2   = 38ull * 512 * 8;
constexpr size_t OFF_U2   = OFF_FT2 + SZ_FT2;         // float [25][512] (U_s @ fc2_w.T)
constexpr size_t SZ_U2    = 25ull * 512 * 4;
constexpr size_t OFF_B2   = OFF_U2 + SZ_U2;           // float [32]
constexpr size_t WS_BYTES = OFF_B2 + 128;

struct Full {
  const float* inputs;
  const float* Wih_t; const float* Whh_t; const float* bih_t; const float* bhh_t;
  const float* Wih_s; const float* Whh_s; const float* bih_s; const float* bhh_s;
  const float* Wih_1; const float* Whh_1; const float* bih_1; const float* bhh_1;
  const float* fc_w;  const float* fc_b;
  const float* fct_w; const float* fct_b;
  const float* fc1_w; const float* fc1_b;
  const float* fc2_w; const float* fc2_b;
  const float* W_x_t; const float* W_h_t; const float* b_t;
  const float* W_x_s; const float* W_h_s; const float* U_s; const float* b_s; const float* b_us;
  char* ws; float* out;
};

typedef _Float16 h2t __attribute__((ext_vector_type(2)));
union U32H { unsigned u; h2t h; unsigned short s[2]; };

__device__ __forceinline__ float sigm(float v) { return 1.f / (1.f + expf(-v)); }
__device__ __forceinline__ float dot2(unsigned a, unsigned b, float c) {
#if __has_builtin(__builtin_amdgcn_fdot2)
  U32H A, B; A.u = a; B.u = b;
  return __builtin_amdgcn_fdot2(A.h, B.h, c, false);
#else
  U32H A, B; A.u = a; B.u = b;
  return fmaf((float)A.h.x, (float)B.h.x, fmaf((float)A.h.y, (float)B.h.y, c));
#endif
}
__device__ __forceinline__ unsigned pack2h(float a, float b) {
  U32H r; r.h.x = (_Float16)a; r.h.y = (_Float16)b; return r.u;
}
__device__ __forceinline__ unsigned short f2h(float a) {
  U32H r; r.u = 0; r.h.x = (_Float16)a; return r.s[0];
}
__device__ __forceinline__ float hlo(unsigned v) { U32H r; r.u = v; return (float)r.h.x; }
__device__ __forceinline__ float hhi(unsigned v) { U32H r; r.u = v; return (float)r.h.y; }

// ---------------- prep: pack weights ----------------
__global__ void prep_pack(Full f) {
  uint4* WHH3 = (uint4*)(f.ws + OFF_WHH3);
  uint4* WX4 = (uint4*)(f.ws + OFF_WX4);
  uint4* WIH3 = (uint4*)(f.ws + OFF_WIH3);
  uint2* FT2 = (uint2*)(f.ws + OFF_FT2);
  float* U2 = (float*)(f.ws + OFF_U2);
  float* B2 = (float*)(f.ws + OFF_B2);

  const size_t N1 = 3ull * 256 * 512;
  const size_t N2 = 256ull * 512;
  const size_t N3 = 3ull * 38 * 512;
  const size_t N4 = 38ull * 512;
  const size_t N5 = 25ull * 512;
  const size_t N6 = 25;
  const size_t TOT = N1 + N2 + N3 + N4 + N5 + N6;
  for (size_t i = (size_t)blockIdx.x * blockDim.x + threadIdx.x; i < TOT;
       i += (size_t)gridDim.x * blockDim.x) {
    if (i < N1) {
      size_t c = i / 131072, r = i % 131072, k2 = r >> 9, u = r & 511;
      const float* W = (c == 0) ? f.Whh_t : (c == 1) ? f.Whh_s : f.Whh_1;
      uint4 v;
#pragma unroll
      for (int g = 0; g < 4; ++g)
        (&v.x)[g] = pack2h(W[(g * 512 + u) * 512 + 2 * k2], W[(g * 512 + u) * 512 + 2 * k2 + 1]);
      WHH3[i] = v;
    } else if (i < N1 + N2) {
      size_t e = i - N1, k2 = e >> 9, u = e & 511;
      uint4 v;
      v.x = pack2h(f.W_x_t[2 * k2 * 512 + u], f.W_x_t[(2 * k2 + 1) * 512 + u]);
      v.y = pack2h(f.W_h_t[2 * k2 * 512 + u], f.W_h_t[(2 * k2 + 1) * 512 + u]);
      v.z = pack2h(f.W_x_s[2 * k2 * 512 + u], f.W_x_s[(2 * k2 + 1) * 512 + u]);
      v.w = pack2h(f.W_h_s[2 * k2 * 512 + u], f.W_h_s[(2 * k2 + 1) * 512 + u]);
      WX4[e] = v;
    } else if (i < N1 + N2 + N3) {
      size_t e = i - N1 - N2, c = e / 19456, r = e % 19456, k2 = r >> 9, u = r & 511;
      const float* W = (c == 0) ? f.Wih_t : (c == 1) ? f.Wih_s : f.Wih_1;
      int k = 2 * (int)k2;
      uint4 v;
#pragma unroll
      for (int g = 0; g < 4; ++g) {
        float a = (k < 75) ? W[(g * 512 + u) * 75 + k] : 0.f;
        float b = (k + 1 < 75) ? W[(g * 512 + u) * 75 + k + 1] : 0.f;
        (&v.x)[g] = pack2h(a, b);
      }
      WIH3[e] = v;
    } else if (i < N1 + N2 + N3 + N4) {
      size_t e = i - N1 - N2 - N3, k2 = e >> 9, u = e & 511;
      int k = 2 * (int)k2;
      uint2 v;
      {
        float a = (k < 75) ? f.fct_w[u * 75 + k] : 0.f;
        float b = (k + 1 < 75) ? f.fct_w[u * 75 + k + 1] : 0.f;
        v.x = pack2h(a, b);
      }
      {
        float a = (k < 75) ? f.fc1_w[u * 75 + k] : 0.f;
        float b = (k + 1 < 75) ? f.fc1_w[u * 75 + k + 1] : 0.f;
        v.y = pack2h(a, b);
      }
      FT2[e] = v;
    } else if (i < N1 + N2 + N3 + N4 + N5) {
      size_t e = i - N1 - N2 - N3 - N4, qi = e >> 9, u = e & 511;
      float acc = 0.f;
      for (int n = 0; n < 512; ++n) acc = fmaf(f.U_s[u * 512 + n], f.fc2_w[qi * 512 + n], acc);
      U2[qi * 512 + u] = acc;
    } else {
      size_t qi = i - N1 - N2 - N3 - N4 - N5;
      float acc = f.fc2_b[qi];
      for (int n = 0; n < 512; ++n) acc = fmaf(f.b_us[n], f.fc2_w[qi * 512 + n], acc);
      B2[qi] = acc;
    }
  }
}

// ---------------- scan: 64 blocks x 512 threads, 2 rows/block, ZERO grid syncs ----------------
__global__ __launch_bounds__(512, 2) void scanB(Full f) {
  const int tid = threadIdx.x;          // unit j
  const int blk = blockIdx.x;           // 0..63
  const int r0 = blk * 2;

  const uint4* WHH3 = (const uint4*)(f.ws + OFF_WHH3);
  const uint4* WX4 = (const uint4*)(f.ws + OFF_WX4);
  const uint4* WIH3 = (const uint4*)(f.ws + OFF_WIH3);
  const uint2* FT2 = (const uint2*)(f.ws + OFF_FT2);
  const float* U2 = (const float*)(f.ws + OFF_U2);
  const float* B2 = (const float*)(f.ws + OFF_B2);

  float* out_logp = f.out;
  float* out_alpha = f.out + B_ * C_;
  float* out_beta = f.out + B_ * C_ + (size_t)T_ * B_ * Q_;

  __shared__ unsigned short hT[2][2][512], hS[2][2][512], h1h[2][2][512];
  __shared__ unsigned short t1h[2][2][512], t2h[2][2][512];
  __shared__ unsigned xp[2][2][40], xg[2][40];
  __shared__ float stf[2][512];
  __shared__ float qp[2][25][8];
  __shared__ float qv[2][32], al[2][32];
  __shared__ float pl[2][60][4];
  __shared__ float lg[2][64];

  // per-thread biases (unit tid)
  const float btb0 = f.bih_t[tid] + f.bhh_t[tid];
  const float btb1 = f.bih_t[512 + tid] + f.bhh_t[512 + tid];
  const float btb2 = f.bih_t[1024 + tid] + f.bhh_t[1024 + tid];
  const float btb3 = f.bih_t[1536 + tid] + f.bhh_t[1536 + tid];
  const float bsb0 = f.bih_s[tid] + f.bhh_s[tid];
  const float bsb1 = f.bih_s[512 + tid] + f.bhh_s[512 + tid];
  const float bsb2 = f.bih_s[1024 + tid] + f.bhh_s[1024 + tid];
  const float bsb3 = f.bih_s[1536 + tid] + f.bhh_s[1536 + tid];
  const float b1b0 = f.bih_1[tid] + f.bhh_1[tid];
  const float b1b1 = f.bih_1[512 + tid] + f.bhh_1[512 + tid];
  const float b1b2 = f.bih_1[1024 + tid] + f.bhh_1[1024 + tid];
  const float b1b3 = f.bih_1[1536 + tid] + f.bhh_1[1536 + tid];
  const float bB = f.b_s[tid] + f.b_t[tid];
  const float bS = f.b_s[tid];
  const float bT1 = f.fct_b[tid], bT2 = f.fc1_b[tid];

  // init state + x(0)
  hT[0][0][tid] = 0; hT[0][1][tid] = 0;
  hS[0][0][tid] = 0; hS[0][1][tid] = 0;
  h1h[0][0][tid] = 0; h1h[0][1][tid] = 0;
  if (tid < 76) {
    const int rr = tid / 38, k2 = tid - rr * 38, k = 2 * k2;
    const float* xb = f.inputs + ((size_t)(r0 + rr) * T_) * IN_;
    const float xa = (k < 75) ? xb[k] : 0.f;
    const float xv = (k + 1 < 75) ? xb[k + 1] : 0.f;
    xp[0][rr][k2] = pack2h(xa, xv);
  }
  __syncthreads();
  {
    float t10 = bT1, t20 = bT2, t11 = bT1, t21 = bT2;
    for (int k2 = 0; k2 < 38; ++k2) {
      const uint2 ft = FT2[(size_t)k2 * 512 + tid];
      const unsigned x0 = xp[0][0][k2], x1 = xp[0][1][k2];
      t10 = dot2(x0, ft.x, t10); t20 = dot2(x0, ft.y, t20);
      t11 = dot2(x1, ft.x, t11); t21 = dot2(x1, ft.y, t21);
    }
    t1h[0][0][tid] = f2h(t10); t1h[0][1][tid] = f2h(t11);
    t2h[0][0][tid] = f2h(t20); t2h[0][1][tid] = f2h(t21);
  }
  __syncthreads();

  float c_t0 = 0, c_t1 = 0, c_s0 = 0, c_s1 = 0, c10 = 0, c11 = 0;

  for (int t = 0; t < T_; ++t) {
    const int cur = t & 1, nxt = cur ^ 1;
    // ---------- phase A: all K=512/1024 GEMVs ----------
    float aT00 = 0, aT01 = 0, aT02 = 0, aT03 = 0, aT10 = 0, aT11 = 0, aT12 = 0, aT13 = 0;
    float aS00 = 0, aS01 = 0, aS02 = 0, aS03 = 0, aS10 = 0, aS11 = 0, aS12 = 0, aS13 = 0;
    float g00 = 0, g01 = 0, g02 = 0, g03 = 0, g10 = 0, g11 = 0, g12 = 0, g13 = 0;
    float aB0 = 0, aB1 = 0, aQ0 = 0, aQ1 = 0;
    {
      const unsigned* hT0 = (const unsigned*)hT[cur][0];
      const unsigned* hT1 = (const unsigned*)hT[cur][1];
      const unsigned* hS0 = (const unsigned*)hS[cur][0];
      const unsigned* hS1 = (const unsigned*)hS[cur][1];
      const unsigned* h10 = (const unsigned*)h1h[cur][0];
      const unsigned* h11 = (const unsigned*)h1h[cur][1];
      const unsigned* t10p = (const unsigned*)t1h[cur][0];
      const unsigned* t11p = (const unsigned*)t1h[cur][1];
      const unsigned* t20p = (const unsigned*)t2h[cur][0];
      const unsigned* t21p = (const unsigned*)t2h[cur][1];
#pragma unroll 2
      for (int k2 = 0; k2 < 256; ++k2) {
        const uint4 wt = WHH3[(size_t)k2 * 512 + tid];
        const uint4 wsv = WHH3[(size_t)(256 + k2) * 512 + tid];
        const uint4 w1v = WHH3[(size_t)(512 + k2) * 512 + tid];
        const uint4 wx = WX4[(size_t)k2 * 512 + tid];
        const unsigned sT0 = hT0[k2], sT1 = hT1[k2];
        const unsigned sS0 = hS0[k2], sS1 = hS1[k2];
        const unsigned s10 = h10[k2], s11 = h11[k2];
        const unsigned v10 = t10p[k2], v11 = t11p[k2];
        const unsigned v20 = t20p[k2], v21 = t21p[k2];
        aT00 = dot2(sT0, wt.x, aT00); aT01 = dot2(sT0, wt.y, aT01);
        aT02 = dot2(sT0, wt.z, aT02); aT03 = dot2(sT0, wt.w, aT03);
        aT10 = dot2(sT1, wt.x, aT10); aT11 = dot2(sT1, wt.y, aT11);
        aT12 = dot2(sT1, wt.z, aT12); aT13 = dot2(sT1, wt.w, aT13);
        aS00 = dot2(sS0, wsv.x, aS00); aS01 = dot2(sS0, wsv.y, aS01);
        aS02 = dot2(sS0, wsv.z, aS02); aS03 = dot2(sS0, wsv.w, aS03);
        aS10 = dot2(sS1, wsv.x, aS10); aS11 = dot2(sS1, wsv.y, aS11);
        aS12 = dot2(sS1, wsv.z, aS12); aS13 = dot2(sS1, wsv.w, aS13);
        g00 = dot2(s10, w1v.x, g00); g01 = dot2(s10, w1v.y, g01);
        g02 = dot2(s10, w1v.z, g02); g03 = dot2(s10, w1v.w, g03);
        g10 = dot2(s11, w1v.x, g10); g11 = dot2(s11, w1v.y, g11);
        g12 = dot2(s11, w1v.z, g12); g13 = dot2(s11, w1v.w, g13);
        aB0 = dot2(v10, wx.x, aB0); aB0 = dot2(sT0, wx.y, aB0);
        aB1 = dot2(v11, wx.x, aB1); aB1 = dot2(sT1, wx.y, aB1);
        aQ0 = dot2(v20, wx.z, aQ0); aQ0 = dot2(sS0, wx.w, aQ0);
        aQ1 = dot2(v21, wx.z, aQ1); aQ1 = dot2(sS1, wx.w, aQ1);
      }
    }
#pragma unroll 2
    for (int k2 = 0; k2 < 38; ++k2) {
      const uint4 wiT = WIH3[(size_t)k2 * 512 + tid];
      const uint4 wiS = WIH3[(size_t)(38 + k2) * 512 + tid];
      const unsigned x0 = xp[cur][0][k2], x1 = xp[cur][1][k2];
      aT00 = dot2(x0, wiT.x, aT00); aT01 = dot2(x0, wiT.y, aT01);
      aT02 = dot2(x0, wiT.z, aT02); aT03 = dot2(x0, wiT.w, aT03);
      aT10 = dot2(x1, wiT.x, aT10); aT11 = dot2(x1, wiT.y, aT11);
      aT12 = dot2(x1, wiT.z, aT12); aT13 = dot2(x1, wiT.w, aT13);
      aS00 = dot2(x0, wiS.x, aS00); aS01 = dot2(x0, wiS.y, aS01);
      aS02 = dot2(x0, wiS.z, aS02); aS03 = dot2(x0, wiS.w, aS03);
      aS10 = dot2(x1, wiS.x, aS10); aS11 = dot2(x1, wiS.y, aS11);
      aS12 = dot2(x1, wiS.z, aS12); aS13 = dot2(x1, wiS.w, aS13);
    }
    // nonlinearities
    {
      const float iv = sigm(aT00 + btb0), fv = sigm(aT01 + btb1);
      const float gv = tanhf(aT02 + btb2), ov = sigm(aT03 + btb3);
      c_t0 = fv * c_t0 + iv * gv;
      hT[nxt][0][tid] = f2h(ov * tanhf(c_t0));
    }
    {
      const float iv = sigm(aT10 + btb0), fv = sigm(aT11 + btb1);
      const float gv = tanhf(aT12 + btb2), ov = sigm(aT13 + btb3);
      c_t1 = fv * c_t1 + iv * gv;
      hT[nxt][1][tid] = f2h(ov * tanhf(c_t1));
    }
    {
      const float iv = sigm(aS00 + bsb0), fv = sigm(aS01 + bsb1);
      const float gv = tanhf(aS02 + bsb2), ov = sigm(aS03 + bsb3);
      c_s0 = fv * c_s0 + iv * gv;
      hS[nxt][0][tid] = f2h(ov * tanhf(c_s0));
    }
    {
      const float iv = sigm(aS10 + bsb0), fv = sigm(aS11 + bsb1);
      const float gv = tanhf(aS12 + bsb2), ov = sigm(aS13 + bsb3);
      c_s1 = fv * c_s1 + iv * gv;
      hS[nxt][1][tid] = f2h(ov * tanhf(c_s1));
    }
    const float bta0 = fmaxf(aB0 + bB, 0.f);
    const float bta1 = fmaxf(aB1 + bB, 0.f);
    out_beta[((size_t)t * B_ + r0) * H_ + tid] = bta0;
    out_beta[((size_t)t * B_ + r0 + 1) * H_ + tid] = bta1;
    stf[0][tid] = tanhf(aQ0 + bS);
    stf[1][tid] = tanhf(aQ1 + bS);
    const float gh00 = g00 + b1b0, gh01 = g01 + b1b1, gh02 = g02 + b1b2, gh03 = g03 + b1b3;
    const float gh10 = g10 + b1b0, gh11 = g11 + b1b1, gh12 = g12 + b1b2, gh13 = g13 + b1b3;
    __syncthreads();

    // ---------- phase B: q partials / reduce / softmax ----------
    {
      const int rr = tid >> 8, rem = tid & 255;
      if (rem < 200) {
        const int qi = rem >> 3, ks = rem & 7;
        const float* u2p = U2 + (size_t)qi * 512 + ks * 64;
        const float* sp = &stf[rr][ks * 64];
        float acc = 0.f;
        for (int j = 0; j < 64; j += 4) {
          const float4 uv = *(const float4*)(u2p + j);
          const float4 sv = *(const float4*)(sp + j);
          acc += sv.x * uv.x + sv.y * uv.y + sv.z * uv.z + sv.w * uv.w;
        }
        qp[rr][qi][ks] = acc;
      }
    }
    __syncthreads();
    {
      const int rr = tid >> 8, rem = tid & 255;
      if (rem < 25) {
        float s = B2[rem];
#pragma unroll
        for (int j = 0; j < 8; ++j) s += qp[rr][rem][j];
        qv[rr][rem] = s;
      }
    }
    __syncthreads();
    {
      const int rr = tid >> 8, rem = tid & 255;
      if (rem < 25) {
        float m = qv[rr][0];
        for (int i2 = 1; i2 < 25; ++i2) m = fmaxf(m, qv[rr][i2]);
        float s = 0.f;
        for (int i2 = 0; i2 < 25; ++i2) s += expf(qv[rr][i2] - m);
        const float a = expf(qv[rr][rem] - m) / s;
        al[rr][rem] = a;
        out_alpha[((size_t)t * B_ + r0 + rr) * Q_ + rem] = a;
      }
    }
    __syncthreads();

    // ---------- phase C: x_gated + x(t+1) staging ----------
    if (tid < 76) {
      const int rr = tid / 38, k2 = tid - rr * 38, k = 2 * k2;
      const unsigned xv = xp[cur][rr][k2];
      const float ga = hlo(xv) * al[rr][k / 3];
      const float gb = (k + 1 < IN_) ? hhi(xv) * al[rr][(k + 1) / 3] : 0.f;
      xg[rr][k2] = pack2h(ga, gb);
      if (t < T_ - 1) {
        const float* xb = f.inputs + ((size_t)(r0 + rr) * T_ + t + 1) * IN_;
        const float xa = (k < 75) ? xb[k] : 0.f;
        const float xc = (k + 1 < 75) ? xb[k + 1] : 0.f;
        xp[nxt][rr][k2] = pack2h(xa, xc);
      }
    }
    __syncthreads();

    // ---------- phase D: tmp(t+1) + cell1 ----------
    if (t < T_ - 1) {
      float t10 = bT1, t20 = bT2, t11 = bT1, t21 = bT2;
      for (int k2 = 0; k2 < 38; ++k2) {
        const uint2 ft = FT2[(size_t)k2 * 512 + tid];
        const unsigned x0 = xp[nxt][0][k2], x1 = xp[nxt][1][k2];
        t10 = dot2(x0, ft.x, t10); t20 = dot2(x0, ft.y, t20);
        t11 = dot2(x1, ft.x, t11); t21 = dot2(x1, ft.y, t21);
      }
      t1h[nxt][0][tid] = f2h(t10); t1h[nxt][1][tid] = f2h(t11);
      t2h[nxt][0][tid] = f2h(t20); t2h[nxt][1][tid] = f2h(t21);
    }
    {
      float cx00 = 0, cx01 = 0, cx02 = 0, cx03 = 0, cx10 = 0, cx11 = 0, cx12 = 0, cx13 = 0;
#pragma unroll 2
      for (int k2 = 0; k2 < 38; ++k2) {
        const uint4 w1 = WIH3[(size_t)(76 + k2) * 512 + tid];
        const unsigned x0 = xg[0][k2], x1 = xg[1][k2];
        cx00 = dot2(x0, w1.x, cx00); cx01 = dot2(x0, w1.y, cx01);
        cx02 = dot2(x0, w1.z, cx02); cx03 = dot2(x0, w1.w, cx03);
        cx10 = dot2(x1, w1.x, cx10); cx11 = dot2(x1, w1.y, cx11);
        cx12 = dot2(x1, w1.z, cx12); cx13 = dot2(x1, w1.w, cx13);
      }
      {
        const float i1 = sigm(cx00 + gh00), f1 = sigm(cx01 + gh01);
        const float gg = tanhf(cx02 + gh02), o1 = sigm(cx03 + gh03);
        c10 = f1 * c10 + i1 * gg;
        h1h[nxt][0][tid] = f2h(o1 * tanhf(c10) * bta0);
      }
      {
        const float i1 = sigm(cx10 + gh10), f1 = sigm(cx11 + gh11);
        const float gg = tanhf(cx12 + gh12), o1 = sigm(cx13 + gh13);
        c11 = f1 * c11 + i1 * gg;
        h1h[nxt][1][tid] = f2h(o1 * tanhf(c11) * bta1);
      }
    }
    __syncthreads();
  }

  // ---------- epilogue: logits + log_softmax (final h1 in buffer 0) ----------
  if (tid < 480) {
    const int rr = tid / 240, rem = tid % 240, ci = rem >> 2, ks = rem & 3;
    const float* fr = f.fc_w + (size_t)ci * 512 + ks * 128;
    const unsigned* hp = (const unsigned*)h1h[0][rr];
    float acc = 0.f;
    for (int e = 0; e < 64; ++e) {
      const unsigned v = hp[ks * 64 + e];
      acc = fmaf(hlo(v), fr[2 * e], acc);
      acc = fmaf(hhi(v), fr[2 * e + 1], acc);
    }
    pl[rr][ci][ks] = acc;
  }
  __syncthreads();
  if (tid < 120) {
    const int rr = tid / 60, ci = tid % 60;
    lg[rr][ci] = f.fc_b[ci] + pl[rr][ci][0] + pl[rr][ci][1] + pl[rr][ci][2] + pl[rr][ci][3];
  }
  __syncthreads();
  if (tid < 120) {
    const int rr = tid / 60, ci = tid % 60;
    float m = lg[rr][0];
    for (int i2 = 1; i2 < 60; ++i2) m = fmaxf(m, lg[rr][i2]);
    float s = 0.f;
    for (int i2 = 0; i2 < 60; ++i2) s += expf(lg[rr][i2] - m);
    out_logp[(size_t)(r0 + rr) * C_ + ci] = lg[rr][ci] - m - logf(s);
  }
}

extern "C" void kernel_launch(void* const* d_in, const int* in_sizes, int n_in,
                              void* d_out, int out_size, void* d_ws, size_t ws_size,
                              hipStream_t stream) {
  if (ws_size < WS_BYTES) return;  // fail loudly (output stays poisoned)

  Full f;
  f.inputs = (const float*)d_in[0];
  f.Wih_t = (const float*)d_in[2];  f.Whh_t = (const float*)d_in[3];
  f.bih_t = (const float*)d_in[4];  f.bhh_t = (const float*)d_in[5];
  f.Wih_s = (const float*)d_in[6];  f.Whh_s = (const float*)d_in[7];
  f.bih_s = (const float*)d_in[8];  f.bhh_s = (const float*)d_in[9];
  f.Wih_1 = (const float*)d_in[10]; f.Whh_1 = (const float*)d_in[11];
  f.bih_1 = (const float*)d_in[12]; f.bhh_1 = (const float*)d_in[13];
  f.fc_w  = (const float*)d_in[14]; f.fc_b  = (const float*)d_in[15];
  f.fct_w = (const float*)d_in[16]; f.fct_b = (const float*)d_in[17];
  f.fc1_w = (const float*)d_in[18]; f.fc1_b = (const float*)d_in[19];
  f.fc2_w = (const float*)d_in[20]; f.fc2_b = (const float*)d_in[21];
  f.W_x_t = (const float*)d_in[22]; f.W_h_t = (const float*)d_in[23];
  f.b_t   = (const float*)d_in[24];
  f.W_x_s = (const float*)d_in[25]; f.W_h_s = (const float*)d_in[26];
  f.U_s   = (const float*)d_in[27]; f.b_s   = (const float*)d_in[28];
  f.b_us  = (const float*)d_in[29];
  f.ws = (char*)d_ws;
  f.out = (float*)d_out;

  hipLaunchKernelGGL(prep_pack, dim3(512), dim3(256), 0, stream, f);
  hipLaunchKernelGGL(scanB, dim3(64), dim3(512), 0, stream, f);
}